// Round 14
// baseline (233.794 us; speedup 1.0000x reference)
//
#include <hip/hip_runtime.h>
#include <stdint.h>

typedef __attribute__((ext_vector_type(8))) short short8;
typedef __attribute__((ext_vector_type(4))) float f32x4;
typedef __attribute__((ext_vector_type(8))) unsigned short u16x8;
typedef __attribute__((ext_vector_type(2))) unsigned int u32x2;

#define DEV static __device__ __forceinline__

DEV unsigned short f2bf(float f) {
  union { float f; uint32_t u; } v; v.f = f;
  uint32_t r = v.u + 0x7FFFu + ((v.u >> 16) & 1u);
  return (unsigned short)(r >> 16);
}

DEV void gload16(const void* g, void* l) {
  __builtin_amdgcn_global_load_lds(
      (const __attribute__((address_space(1))) void*)g,
      (__attribute__((address_space(3))) void*)l, 16, 0, 0);
}

// ---------------- cast x (f32 -> bf16), 8 elems/thread ----------------
__global__ void cast_x_kernel(const float* __restrict__ x, unsigned short* __restrict__ xb) {
  int i = blockIdx.x * 256 + threadIdx.x;
  f32x4 a = ((const f32x4*)x)[2 * i];
  f32x4 b = ((const f32x4*)x)[2 * i + 1];
  u16x8 o;
  o[0] = f2bf(a[0]); o[1] = f2bf(a[1]); o[2] = f2bf(a[2]); o[3] = f2bf(a[3]);
  o[4] = f2bf(b[0]); o[5] = f2bf(b[1]); o[6] = f2bf(b[2]); o[7] = f2bf(b[3]);
  ((u16x8*)xb)[i] = o;
}

// ---------------- transpose + cast W (K,N)f32 -> Wt (N,K)bf16 ----------------
__global__ void transpose_w_kernel(const float* __restrict__ Wq, const float* __restrict__ Wk,
                                   const float* __restrict__ Wv, const float* __restrict__ Wo,
                                   unsigned short* __restrict__ wt) {
  __shared__ float tile[64][65];
  int z = blockIdx.z;
  const float* W = (z == 0) ? Wq : (z == 1) ? Wk : (z == 2) ? Wv : Wo;
  unsigned short* dst = wt + (size_t)z * 1024 * 1024;
  int bn = blockIdx.x, bk = blockIdx.y;
  int t = threadIdx.x;
  int c = t & 63, rr = t >> 6;
#pragma unroll
  for (int p = 0; p < 16; ++p) {
    int r = p * 4 + rr;
    tile[r][c] = W[(size_t)(bk * 64 + r) * 1024 + bn * 64 + c];
  }
  __syncthreads();
#pragma unroll
  for (int p = 0; p < 16; ++p) {
    int r2 = p * 4 + rr;
    dst[(size_t)(bn * 64 + r2) * 1024 + bk * 64 + c] = f2bf(tile[c][r2]);
  }
}

// ---------------- fused QKV GEMM: A in LDS (BK=64), B direct from L2 ----------------
// LDS = A double-buffer only (32KB) -> 3 blocks/CU. Per iter: LOADB(regs,8) +
// STAGE_A(4) -> vmcnt(12) -> barrier -> ds_read A + MFMA -> barrier.
// B panels are L2-resident (each read by 64 bm-blocks); moves B reads off the
// LDS pipe (which was the binding constraint at 128^2: 941cy LDS vs 621cy MFMA).
__global__ __launch_bounds__(256, 3) void gemm_qkv(const unsigned short* __restrict__ A,
                                                   const unsigned short* __restrict__ wt,
                                                   unsigned short* __restrict__ Qb,
                                                   unsigned short* __restrict__ Kb,
                                                   unsigned short* __restrict__ Vtb,
                                                   float qscale) {
  constexpr int K = 1024;
  __shared__ __align__(16) unsigned short As[2][128 * 64];
  int flat = blockIdx.x + 24 * blockIdx.y;
  int xcd = flat & 7, idx = flat >> 3;      // idx 0..191
  int bm = xcd * 8 + (idx & 7);             // per-XCD M-chunk (A L2-resident)
  int bn = idx >> 3;                        // 0..23
  int which = bn >> 3, bnn = bn & 7;
  int tid = threadIdx.x, lane = tid & 63, w = tid >> 6;
  int wr = w >> 1, wc = w & 1;
  int g2 = lane >> 4;
  f32x4 acc[4][4] = {};

  // A staging: 16KB tile = 16 chunks of 1KB; wave w stages chunks w*4..w*4+3
  int srg[4], sof[4];
#pragma unroll
  for (int i = 0; i < 4; ++i) {
    int ci = w * 4 + i;
    int r = ci * 8 + (lane >> 3);
    srg[i] = r;
    sof[i] = ((lane & 7) ^ (r & 7)) * 8;
  }
  const unsigned short* Arow = A + (size_t)(bm * 128) * K;
  const unsigned short* BrowG = wt + (size_t)which * 1048576 + (size_t)(bnn * 128) * K;

  auto STAGE_A = [&](int bi, int k0) {
#pragma unroll
    for (int i = 0; i < 4; ++i)
      gload16(Arow + (size_t)srg[i] * K + k0 + sof[i], &As[bi][(w * 4 + i) * 512]);
  };
  auto LOADB = [&](short8 (&bf)[4][2], int k0) {
#pragma unroll
    for (int n = 0; n < 4; ++n)
#pragma unroll
      for (int s = 0; s < 2; ++s)
        bf[n][s] = *(const short8*)(BrowG + (size_t)(wc * 64 + n * 16 + (lane & 15)) * K + k0 + s * 32 + g2 * 8);
  };

  STAGE_A(0, 0);
  for (int kt = 0; kt < 16; ++kt) {
    int cur = kt & 1;
    short8 bf[4][2];
    LOADB(bf, kt * 64);
    if (kt < 15) {
      STAGE_A(cur ^ 1, (kt + 1) * 64);
      asm volatile("s_waitcnt vmcnt(12)" ::: "memory");  // A(kt) landed; B(kt)8+A(kt+1)4 in flight... (B waited by compiler at use)
    } else {
      asm volatile("s_waitcnt vmcnt(8)" ::: "memory");   // A(15) landed; B(15) in flight
    }
    __builtin_amdgcn_s_barrier();
    __builtin_amdgcn_sched_barrier(0);
    short8 af[2][4];
#pragma unroll
    for (int s = 0; s < 2; ++s)
#pragma unroll
      for (int m = 0; m < 4; ++m) {
        int ra = wr * 64 + m * 16 + (lane & 15);
        af[s][m] = *(const short8*)(&As[cur][ra * 64 + (((g2 + 4 * s) ^ (ra & 7)) * 8)]);
      }
#pragma unroll
    for (int s = 0; s < 2; ++s)
#pragma unroll
      for (int m = 0; m < 4; ++m)
#pragma unroll
        for (int n = 0; n < 4; ++n)
          acc[m][n] = __builtin_amdgcn_mfma_f32_16x16x32_bf16(af[s][m], bf[n][s], acc[m][n], 0, 0, 0);
    __builtin_amdgcn_s_barrier();
    __builtin_amdgcn_sched_barrier(0);
  }

  int rbase = bm * 128 + wr * 64;
  int cbase = bnn * 128 + wc * 64;
#pragma unroll
  for (int m = 0; m < 4; ++m)
#pragma unroll
    for (int n = 0; n < 4; ++n) {
      int row0 = rbase + m * 16 + (lane >> 4) * 4;
      int col = cbase + n * 16 + (lane & 15);
      int h = col >> 6, d = col & 63;
      int b = row0 >> 12, s0 = row0 & 4095;
      if (which == 0) {
#pragma unroll
        for (int reg = 0; reg < 4; ++reg)
          Qb[((size_t)(b * 16 + h) * 4096 + s0 + reg) * 64 + d] = f2bf(acc[m][n][reg] * qscale);
      } else if (which == 1) {
#pragma unroll
        for (int reg = 0; reg < 4; ++reg)
          Kb[((size_t)(b * 16 + h) * 4096 + s0 + reg) * 64 + d] = f2bf(acc[m][n][reg]);
      } else {
        u32x2 pk;
        asm("v_cvt_pk_bf16_f32 %0, %1, %2" : "=v"(pk[0]) : "v"(acc[m][n][0]), "v"(acc[m][n][1]));
        asm("v_cvt_pk_bf16_f32 %0, %1, %2" : "=v"(pk[1]) : "v"(acc[m][n][2]), "v"(acc[m][n][3]));
        *(u32x2*)(Vtb + ((((size_t)(b * 16 + h) * 64 + (s0 >> 6)) * 64 + d) * 64 + (s0 & 63))) = pk;
      }
    }
}

// ---------------- output GEMM: f32 out (same hybrid A-LDS / B-L2) ----------------
__global__ __launch_bounds__(256, 3) void gemm_out(const unsigned short* __restrict__ A,
                                                   const unsigned short* __restrict__ Bt,
                                                   float* __restrict__ dst) {
  constexpr int K = 1024;
  __shared__ __align__(16) unsigned short As[2][128 * 64];
  int flat = blockIdx.x + 8 * blockIdx.y;
  int xcd = flat & 7, idx = flat >> 3;      // idx 0..63
  int bm = xcd * 8 + (idx & 7);
  int bn = idx >> 3;                        // 0..7
  int tid = threadIdx.x, lane = tid & 63, w = tid >> 6;
  int wr = w >> 1, wc = w & 1;
  int g2 = lane >> 4;
  f32x4 acc[4][4] = {};

  int srg[4], sof[4];
#pragma unroll
  for (int i = 0; i < 4; ++i) {
    int ci = w * 4 + i;
    int r = ci * 8 + (lane >> 3);
    srg[i] = r;
    sof[i] = ((lane & 7) ^ (r & 7)) * 8;
  }
  const unsigned short* Arow = A + (size_t)(bm * 128) * K;
  const unsigned short* BrowG = Bt + (size_t)(bn * 128) * K;

  auto STAGE_A = [&](int bi, int k0) {
#pragma unroll
    for (int i = 0; i < 4; ++i)
      gload16(Arow + (size_t)srg[i] * K + k0 + sof[i], &As[bi][(w * 4 + i) * 512]);
  };
  auto LOADB = [&](short8 (&bf)[4][2], int k0) {
#pragma unroll
    for (int n = 0; n < 4; ++n)
#pragma unroll
      for (int s = 0; s < 2; ++s)
        bf[n][s] = *(const short8*)(BrowG + (size_t)(wc * 64 + n * 16 + (lane & 15)) * K + k0 + s * 32 + g2 * 8);
  };

  STAGE_A(0, 0);
  for (int kt = 0; kt < 16; ++kt) {
    int cur = kt & 1;
    short8 bf[4][2];
    LOADB(bf, kt * 64);
    if (kt < 15) {
      STAGE_A(cur ^ 1, (kt + 1) * 64);
      asm volatile("s_waitcnt vmcnt(12)" ::: "memory");
    } else {
      asm volatile("s_waitcnt vmcnt(8)" ::: "memory");
    }
    __builtin_amdgcn_s_barrier();
    __builtin_amdgcn_sched_barrier(0);
    short8 af[2][4];
#pragma unroll
    for (int s = 0; s < 2; ++s)
#pragma unroll
      for (int m = 0; m < 4; ++m) {
        int ra = wr * 64 + m * 16 + (lane & 15);
        af[s][m] = *(const short8*)(&As[cur][ra * 64 + (((g2 + 4 * s) ^ (ra & 7)) * 8)]);
      }
#pragma unroll
    for (int s = 0; s < 2; ++s)
#pragma unroll
      for (int m = 0; m < 4; ++m)
#pragma unroll
        for (int n = 0; n < 4; ++n)
          acc[m][n] = __builtin_amdgcn_mfma_f32_16x16x32_bf16(af[s][m], bf[n][s], acc[m][n], 0, 0, 0);
    __builtin_amdgcn_s_barrier();
    __builtin_amdgcn_sched_barrier(0);
  }

  int rbase = bm * 128 + wr * 64;
  int cbase = bn * 128 + wc * 64;
#pragma unroll
  for (int m = 0; m < 4; ++m)
#pragma unroll
    for (int n = 0; n < 4; ++n) {
      int row0 = rbase + m * 16 + (lane >> 4) * 4;
      int col = cbase + n * 16 + (lane & 15);
#pragma unroll
      for (int reg = 0; reg < 4; ++reg)
        dst[(size_t)(row0 + reg) * 1024 + col] = acc[m][n][reg];
    }
}

// ---------------- sparse attention (unchanged from R12) ----------------
__global__ __launch_bounds__(256) void attn_kernel(const unsigned short* __restrict__ Qh,
                            const unsigned short* __restrict__ Kh,
                            const unsigned short* __restrict__ Vbt,
                            const int* __restrict__ bidx,
                            unsigned short* __restrict__ attn_out,
                            float* __restrict__ Opart,
                            float* __restrict__ lpart) {
  __shared__ __align__(16) unsigned short Ks[3][64 * 64];
  __shared__ __align__(16) unsigned short Vs[3][64 * 64];
  int flat = blockIdx.x + 71 * blockIdx.y;
  int nf = (flat & 7) * 284 + (flat >> 3);  // bijective chunked XCD swizzle
  int gx = nf % 71, bh = nf / 71;
  int h = bh & 15;
  int tid = threadIdx.x, lane = tid & 63, w = tid >> 6;
  int q = lane & 15, g = lane >> 4;
  float slope2 = exp2f(-0.5f * (float)(h + 1)) * 1.44269504f;  // slope * log2(e)

  int qb, nkb;
  int vlist;
  if (gx < 63) {
    qb = gx + 1;
    int v = -1;
    if (lane == 0) v = 0;
    else if (lane <= 12) v = bidx[qb * 12 + (lane - 1)];
    vlist = v;
    unsigned long long msk = __ballot(v >= 0);
    nkb = __builtin_popcountll(msk & 0x1FFFull);
  } else {
    qb = 0;
    nkb = 8;
    vlist = (gx - 63) * 8 + lane;  // lanes 0..7 hold the chunk's blocks
  }

  int qrow = qb * 64 + w * 16 + q;
  const unsigned short* qptr = Qh + ((size_t)bh * 4096 + qrow) * 64 + g * 8;
  short8 qf0 = *(const short8*)qptr;
  short8 qf1 = *(const short8*)(qptr + 32);

  float qposf = (float)qrow;
  float sq = slope2 * qposf;
  float er[4][4];
#pragma unroll
  for (int ct = 0; ct < 4; ++ct)
#pragma unroll
    for (int r = 0; r < 4; ++r) er[ct][r] = slope2 * (float)(ct * 16 + r);

  float psum = 0.f;
  f32x4 accO[4] = {};

  const unsigned short* Kbh = Kh + (size_t)bh * 4096 * 64;
  const unsigned short* Vbh = Vbt + (size_t)bh * 4096 * 64;

  int srr[2], so[2];
#pragma unroll
  for (int i = 0; i < 2; ++i) {
    int ci = w * 2 + i;
    int r = ci * 8 + (lane >> 3);
    srr[i] = r;
    so[i] = ((lane & 7) ^ (r & 7)) * 8;
  }
  auto STAGE = [&](int bi, int kb) {
    const unsigned short* kbase = Kbh + (size_t)kb * 4096;
    const unsigned short* vbase = Vbh + (size_t)kb * 4096;
#pragma unroll
    for (int i = 0; i < 2; ++i) {
      gload16(kbase + srr[i] * 64 + so[i], &Ks[bi][(w * 2 + i) * 512]);
      gload16(vbase + srr[i] * 64 + so[i], &Vs[bi][(w * 2 + i) * 512]);
    }
  };

  STAGE(0, __builtin_amdgcn_readlane(vlist, 0));
  STAGE(1, __builtin_amdgcn_readlane(vlist, 1));

  for (int it = 0; it < nkb; ++it) {
    int cur = it % 3;
    int kb = __builtin_amdgcn_readlane(vlist, it);
    if (it + 1 < nkb) {
      asm volatile("s_waitcnt vmcnt(4)" ::: "memory");  // tile it landed; it+1 in flight
    } else {
      asm volatile("s_waitcnt vmcnt(0)" ::: "memory");
    }
    __builtin_amdgcn_s_barrier();
    __builtin_amdgcn_sched_barrier(0);
    if (it + 2 < nkb) STAGE((it + 2) % 3, __builtin_amdgcn_readlane(vlist, it + 2));

    float kb4g = (float)(kb * 64 + 4 * g);
    float d_[4][4];
    if (kb != qb) {
      if (kb < qb) {
        float t = __builtin_fmaf(slope2, kb4g, -sq);
#pragma unroll
        for (int ct = 0; ct < 4; ++ct)
#pragma unroll
          for (int r = 0; r < 4; ++r) d_[ct][r] = t + er[ct][r];
      } else {
        float t = sq - slope2 * kb4g;
#pragma unroll
        for (int ct = 0; ct < 4; ++ct)
#pragma unroll
          for (int r = 0; r < 4; ++r) d_[ct][r] = t - er[ct][r];
      }
    } else {
      float db = qposf - kb4g;
#pragma unroll
      for (int ct = 0; ct < 4; ++ct)
#pragma unroll
        for (int r = 0; r < 4; ++r)
          d_[ct][r] = -slope2 * fabsf(db - (float)(ct * 16 + r));
    }

    float pv[4][4];
    __builtin_amdgcn_s_setprio(1);
#pragma unroll
    for (int ct = 0; ct < 4; ++ct) {
      int kr = ct * 16 + q;
      short8 kf0 = *(const short8*)(&Ks[cur][kr * 64 + ((g ^ (kr & 7)) * 8)]);
      short8 kf1 = *(const short8*)(&Ks[cur][kr * 64 + (((g + 4) ^ (kr & 7)) * 8)]);
      f32x4 cin = {d_[ct][0], d_[ct][1], d_[ct][2], d_[ct][3]};
      f32x4 s = __builtin_amdgcn_mfma_f32_16x16x32_bf16(kf0, qf0, cin, 0, 0, 0);
      s = __builtin_amdgcn_mfma_f32_16x16x32_bf16(kf1, qf1, s, 0, 0, 0);
#pragma unroll
      for (int r = 0; r < 4; ++r) {
        float p = exp2f(s[r]);
        pv[ct][r] = p;
        psum += p;
      }
    }
    __builtin_amdgcn_s_setprio(0);

    // in-register P^T -> PV A-fragment redistribution (T12)
    uint32_t pkw[4][2];
#pragma unroll
    for (int ct = 0; ct < 4; ++ct) {
      asm("v_cvt_pk_bf16_f32 %0, %1, %2" : "=v"(pkw[ct][0]) : "v"(pv[ct][0]), "v"(pv[ct][1]));
      asm("v_cvt_pk_bf16_f32 %0, %1, %2" : "=v"(pkw[ct][1]) : "v"(pv[ct][2]), "v"(pv[ct][3]));
    }
    bool odd = (tid & 16) != 0;
    short8 pa[2];
#pragma unroll
    for (int f = 0; f < 2; ++f) {
      uint32_t s0 = pkw[2 * f][0], s1 = pkw[2 * f][1];
      uint32_t t0 = pkw[2 * f + 1][0], t1 = pkw[2 * f + 1][1];
      asm("v_permlane32_swap_b32 %0, %1" : "+v"(s0), "+v"(t0));
      asm("v_permlane32_swap_b32 %0, %1" : "+v"(s1), "+v"(t1));
      uint32_t xs0 = (uint32_t)__shfl_xor((int)s0, 16, 64);
      uint32_t xs1 = (uint32_t)__shfl_xor((int)s1, 16, 64);
      uint32_t xt0 = (uint32_t)__shfl_xor((int)t0, 16, 64);
      uint32_t xt1 = (uint32_t)__shfl_xor((int)t1, 16, 64);
      union { uint32_t w[4]; short8 v; } u;
      u.w[0] = odd ? xt0 : s0;
      u.w[1] = odd ? xt1 : s1;
      u.w[2] = odd ? t0 : xs0;
      u.w[3] = odd ? t1 : xs1;
      pa[f] = u.v;
    }

    __builtin_amdgcn_s_setprio(1);
#pragma unroll
    for (int dt = 0; dt < 4; ++dt) {
      int dr = dt * 16 + q;
      short8 vf0 = *(const short8*)(&Vs[cur][dr * 64 + ((g ^ (dr & 7)) * 8)]);
      short8 vf1 = *(const short8*)(&Vs[cur][dr * 64 + (((g + 4) ^ (dr & 7)) * 8)]);
      accO[dt] = __builtin_amdgcn_mfma_f32_16x16x32_bf16(pa[0], vf0, accO[dt], 0, 0, 0);
      accO[dt] = __builtin_amdgcn_mfma_f32_16x16x32_bf16(pa[1], vf1, accO[dt], 0, 0, 0);
    }
    __builtin_amdgcn_s_setprio(0);
  }

  float lt = psum;
  lt += __shfl_xor(lt, 16, 64);
  lt += __shfl_xor(lt, 32, 64);

  int b = bh >> 4;
  if (gx < 63) {
#pragma unroll
    for (int reg = 0; reg < 4; ++reg) {
      float ls = __shfl(lt, 4 * g + reg, 64);
      float rl = 1.0f / ls;
      int row = qb * 64 + w * 16 + 4 * g + reg;
#pragma unroll
      for (int dt = 0; dt < 4; ++dt) {
        int col = h * 64 + dt * 16 + q;
        attn_out[((size_t)b * 4096 + row) * 1024 + col] = f2bf(accO[dt][reg] * rl);
      }
    }
  } else {
    int chunk = gx - 63;
    float* Op = Opart + (size_t)(bh * 8 + chunk) * 64 * 64;
    float* lp = lpart + (size_t)(bh * 8 + chunk) * 64;
#pragma unroll
    for (int reg = 0; reg < 4; ++reg) {
      int row = w * 16 + 4 * g + reg;
#pragma unroll
      for (int dt = 0; dt < 4; ++dt) {
        int col = dt * 16 + q;
        Op[row * 64 + col] = accO[dt][reg];
      }
    }
    if (g == 0) lp[w * 16 + q] = lt;
  }
}

// ---------------- merge the 8 qb=0 chunks ----------------
__global__ void merge_qb0(const float* __restrict__ Opart, const float* __restrict__ lpart,
                          unsigned short* __restrict__ attn_out) {
  int bh = blockIdx.x;
  int tid = threadIdx.x;
  int row = tid >> 2, cg = tid & 3;
  const float* lp = lpart + (size_t)bh * 8 * 64;
  float L = 0.f;
#pragma unroll
  for (int c = 0; c < 8; ++c) L += lp[c * 64 + row];
  float rL = 1.0f / L;
  int b = bh >> 4, h = bh & 15;
  f32x4 acc0 = {}, acc1 = {}, acc2 = {}, acc3 = {};
#pragma unroll
  for (int c = 0; c < 8; ++c) {
    const float* Op = Opart + ((size_t)(bh * 8 + c) * 64 + row) * 64 + cg * 16;
    acc0 += ((const f32x4*)Op)[0];
    acc1 += ((const f32x4*)Op)[1];
    acc2 += ((const f32x4*)Op)[2];
    acc3 += ((const f32x4*)Op)[3];
  }
  unsigned short* out = attn_out + ((size_t)b * 4096 + row) * 1024 + h * 64 + cg * 16;
#pragma unroll
  for (int j = 0; j < 4; ++j) {
    out[j] = f2bf(acc0[j] * rL);
    out[4 + j] = f2bf(acc1[j] * rL);
    out[8 + j] = f2bf(acc2[j] * rL);
    out[12 + j] = f2bf(acc3[j] * rL);
  }
}

extern "C" void kernel_launch(void* const* d_in, const int* in_sizes, int n_in,
                              void* d_out, int out_size, void* d_ws, size_t ws_size,
                              hipStream_t stream) {
  const float* x = (const float*)d_in[0];
  const float* Wq = (const float*)d_in[1];
  const float* Wk = (const float*)d_in[2];
  const float* Wv = (const float*)d_in[3];
  const float* Wo = (const float*)d_in[4];
  const int* bidx = (const int*)d_in[5];

  char* ws = (char*)d_ws;
  unsigned short* xb = (unsigned short*)(ws);
  unsigned short* wt = (unsigned short*)(ws + 16777216);
  unsigned short* Qb = (unsigned short*)(ws + 25165824);
  unsigned short* Kb = (unsigned short*)(ws + 41943040);
  unsigned short* Vtb = (unsigned short*)(ws + 58720256);
  unsigned short* attnb = (unsigned short*)(ws + 75497472);
  float* Opart = (float*)(ws);
  float* lpart = (float*)(ws + 4194304);

  cast_x_kernel<<<4096, 256, 0, stream>>>(x, xb);
  transpose_w_kernel<<<dim3(16, 16, 4), 256, 0, stream>>>(Wq, Wk, Wv, Wo, wt);
  gemm_qkv<<<dim3(24, 64), 256, 0, stream>>>(xb, wt, Qb, Kb, Vtb, 0.18033688f);
  attn_kernel<<<dim3(71, 32), 256, 0, stream>>>(Qb, Kb, Vtb, bidx, attnb, Opart, lpart);
  merge_qb0<<<32, 256, 0, stream>>>(Opart, lpart, attnb);
  gemm_out<<<dim3(8, 64), 256, 0, stream>>>(attnb, wt + 3145728, (float*)d_out);
}

// Round 15
// 165.473 us; speedup vs baseline: 1.4129x; 1.4129x over previous
//
#include <hip/hip_runtime.h>
#include <stdint.h>

typedef __attribute__((ext_vector_type(8))) short short8;
typedef __attribute__((ext_vector_type(4))) float f32x4;
typedef __attribute__((ext_vector_type(8))) unsigned short u16x8;
typedef __attribute__((ext_vector_type(2))) unsigned int u32x2;

#define DEV static __device__ __forceinline__

DEV unsigned short f2bf(float f) {
  union { float f; uint32_t u; } v; v.f = f;
  uint32_t r = v.u + 0x7FFFu + ((v.u >> 16) & 1u);
  return (unsigned short)(r >> 16);
}

DEV void gload16(const void* g, void* l) {
  __builtin_amdgcn_global_load_lds(
      (const __attribute__((address_space(1))) void*)g,
      (__attribute__((address_space(3))) void*)l, 16, 0, 0);
}

// ---------------- cast x (f32 -> bf16), 8 elems/thread ----------------
__global__ void cast_x_kernel(const float* __restrict__ x, unsigned short* __restrict__ xb) {
  int i = blockIdx.x * 256 + threadIdx.x;
  f32x4 a = ((const f32x4*)x)[2 * i];
  f32x4 b = ((const f32x4*)x)[2 * i + 1];
  u16x8 o;
  o[0] = f2bf(a[0]); o[1] = f2bf(a[1]); o[2] = f2bf(a[2]); o[3] = f2bf(a[3]);
  o[4] = f2bf(b[0]); o[5] = f2bf(b[1]); o[6] = f2bf(b[2]); o[7] = f2bf(b[3]);
  ((u16x8*)xb)[i] = o;
}

// ---------------- transpose + cast W (K,N)f32 -> Wt (N,K)bf16 ----------------
__global__ void transpose_w_kernel(const float* __restrict__ Wq, const float* __restrict__ Wk,
                                   const float* __restrict__ Wv, const float* __restrict__ Wo,
                                   unsigned short* __restrict__ wt) {
  __shared__ float tile[64][65];
  int z = blockIdx.z;
  const float* W = (z == 0) ? Wq : (z == 1) ? Wk : (z == 2) ? Wv : Wo;
  unsigned short* dst = wt + (size_t)z * 1024 * 1024;
  int bn = blockIdx.x, bk = blockIdx.y;
  int t = threadIdx.x;
  int c = t & 63, rr = t >> 6;
#pragma unroll
  for (int p = 0; p < 16; ++p) {
    int r = p * 4 + rr;
    tile[r][c] = W[(size_t)(bk * 64 + r) * 1024 + bn * 64 + c];
  }
  __syncthreads();
#pragma unroll
  for (int p = 0; p < 16; ++p) {
    int r2 = p * 4 + rr;
    dst[(size_t)(bn * 64 + r2) * 1024 + bk * 64 + c] = f2bf(tile[c][r2]);
  }
}

// ---------------- fused QKV GEMM (R12 config: BK=64, counted-vmcnt 2-phase) ----------------
__global__ __launch_bounds__(256, 2) void gemm_qkv(const unsigned short* __restrict__ A,
                                                   const unsigned short* __restrict__ wt,
                                                   unsigned short* __restrict__ Qb,
                                                   unsigned short* __restrict__ Kb,
                                                   unsigned short* __restrict__ Vtb,
                                                   float qscale) {
  constexpr int K = 1024;
  __shared__ __align__(16) unsigned short As[2][128 * 64];
  __shared__ __align__(16) unsigned short Bs[2][128 * 64];
  int flat = blockIdx.x + 24 * blockIdx.y;
  int xcd = flat & 7, idx = flat >> 3;      // idx 0..191
  int bm = xcd * 8 + (idx & 7);             // per-XCD M-chunk (A L2-resident)
  int bn = idx >> 3;                        // 0..23
  int which = bn >> 3, bnn = bn & 7;
  int tid = threadIdx.x, lane = tid & 63, w = tid >> 6;
  int wr = w >> 1, wc = w & 1;
  f32x4 acc[4][4] = {};

  int sr[4], soff[4];
#pragma unroll
  for (int i = 0; i < 4; ++i) {
    int ci = w * 4 + i;
    int r = ci * 8 + (lane >> 3);
    sr[i] = r;
    soff[i] = ((lane & 7) ^ (r & 7)) * 8;
  }
  const unsigned short* Arow = A + (size_t)(bm * 128) * K;
  const unsigned short* Brow = wt + (size_t)which * 1048576 + (size_t)(bnn * 128) * K;

  auto STAGE = [&](int bi, int k0) {
#pragma unroll
    for (int i = 0; i < 4; ++i) {
      gload16(Arow + (size_t)sr[i] * K + k0 + soff[i], &As[bi][(w * 4 + i) * 512]);
      gload16(Brow + (size_t)sr[i] * K + k0 + soff[i], &Bs[bi][(w * 4 + i) * 512]);
    }
  };

  STAGE(0, 0);
  for (int kt = 0; kt < 16; ++kt) {
    int cur = kt & 1;
    if (kt < 15) {
      STAGE(cur ^ 1, (kt + 1) * 64);
      asm volatile("s_waitcnt vmcnt(8)" ::: "memory");
    } else {
      asm volatile("s_waitcnt vmcnt(0)" ::: "memory");
    }
    __builtin_amdgcn_s_barrier();
    __builtin_amdgcn_sched_barrier(0);
    short8 af[2][4], bfr[2][4];
#pragma unroll
    for (int c = 0; c < 2; ++c) {
#pragma unroll
      for (int m = 0; m < 4; ++m) {
        int cc = (lane >> 4) + 4 * c;
        int ra = wr * 64 + m * 16 + (lane & 15);
        af[c][m] = *(const short8*)(&As[cur][ra * 64 + ((cc ^ (ra & 7)) * 8)]);
        int rb = wc * 64 + m * 16 + (lane & 15);
        bfr[c][m] = *(const short8*)(&Bs[cur][rb * 64 + ((cc ^ (rb & 7)) * 8)]);
      }
    }
#pragma unroll
    for (int c = 0; c < 2; ++c)
#pragma unroll
      for (int m = 0; m < 4; ++m)
#pragma unroll
        for (int n = 0; n < 4; ++n)
          acc[m][n] = __builtin_amdgcn_mfma_f32_16x16x32_bf16(af[c][m], bfr[c][n], acc[m][n], 0, 0, 0);
    __builtin_amdgcn_s_barrier();
    __builtin_amdgcn_sched_barrier(0);
  }

  int rbase = bm * 128 + wr * 64;
  int cbase = bnn * 128 + wc * 64;
#pragma unroll
  for (int m = 0; m < 4; ++m)
#pragma unroll
    for (int n = 0; n < 4; ++n) {
      int row0 = rbase + m * 16 + (lane >> 4) * 4;
      int col = cbase + n * 16 + (lane & 15);
      int h = col >> 6, d = col & 63;
      int b = row0 >> 12, s0 = row0 & 4095;
      if (which == 0) {
#pragma unroll
        for (int reg = 0; reg < 4; ++reg)
          Qb[((size_t)(b * 16 + h) * 4096 + s0 + reg) * 64 + d] = f2bf(acc[m][n][reg] * qscale);
      } else if (which == 1) {
#pragma unroll
        for (int reg = 0; reg < 4; ++reg)
          Kb[((size_t)(b * 16 + h) * 4096 + s0 + reg) * 64 + d] = f2bf(acc[m][n][reg]);
      } else {
        u32x2 pk;
        asm("v_cvt_pk_bf16_f32 %0, %1, %2" : "=v"(pk[0]) : "v"(acc[m][n][0]), "v"(acc[m][n][1]));
        asm("v_cvt_pk_bf16_f32 %0, %1, %2" : "=v"(pk[1]) : "v"(acc[m][n][2]), "v"(acc[m][n][3]));
        *(u32x2*)(Vtb + ((((size_t)(b * 16 + h) * 64 + (s0 >> 6)) * 64 + d) * 64 + (s0 & 63))) = pk;
      }
    }
}

// ---------------- output GEMM: f32 out (R12 config) ----------------
__global__ __launch_bounds__(256, 2) void gemm_out(const unsigned short* __restrict__ A,
                                                   const unsigned short* __restrict__ Bt,
                                                   float* __restrict__ dst) {
  constexpr int K = 1024;
  __shared__ __align__(16) unsigned short As[2][128 * 64];
  __shared__ __align__(16) unsigned short Bs[2][128 * 64];
  int flat = blockIdx.x + 8 * blockIdx.y;
  int xcd = flat & 7, idx = flat >> 3;      // idx 0..63
  int bm = xcd * 8 + (idx & 7);
  int bn = idx >> 3;                        // 0..7
  int tid = threadIdx.x, lane = tid & 63, w = tid >> 6;
  int wr = w >> 1, wc = w & 1;
  f32x4 acc[4][4] = {};

  int sr[4], soff[4];
#pragma unroll
  for (int i = 0; i < 4; ++i) {
    int ci = w * 4 + i;
    int r = ci * 8 + (lane >> 3);
    sr[i] = r;
    soff[i] = ((lane & 7) ^ (r & 7)) * 8;
  }
  const unsigned short* Arow = A + (size_t)(bm * 128) * K;
  const unsigned short* Brow = Bt + (size_t)(bn * 128) * K;

  auto STAGE = [&](int bi, int k0) {
#pragma unroll
    for (int i = 0; i < 4; ++i) {
      gload16(Arow + (size_t)sr[i] * K + k0 + soff[i], &As[bi][(w * 4 + i) * 512]);
      gload16(Brow + (size_t)sr[i] * K + k0 + soff[i], &Bs[bi][(w * 4 + i) * 512]);
    }
  };

  STAGE(0, 0);
  for (int kt = 0; kt < 16; ++kt) {
    int cur = kt & 1;
    if (kt < 15) {
      STAGE(cur ^ 1, (kt + 1) * 64);
      asm volatile("s_waitcnt vmcnt(8)" ::: "memory");
    } else {
      asm volatile("s_waitcnt vmcnt(0)" ::: "memory");
    }
    __builtin_amdgcn_s_barrier();
    __builtin_amdgcn_sched_barrier(0);
    short8 af[2][4], bfr[2][4];
#pragma unroll
    for (int c = 0; c < 2; ++c) {
#pragma unroll
      for (int m = 0; m < 4; ++m) {
        int cc = (lane >> 4) + 4 * c;
        int ra = wr * 64 + m * 16 + (lane & 15);
        af[c][m] = *(const short8*)(&As[cur][ra * 64 + ((cc ^ (ra & 7)) * 8)]);
        int rb = wc * 64 + m * 16 + (lane & 15);
        bfr[c][m] = *(const short8*)(&Bs[cur][rb * 64 + ((cc ^ (rb & 7)) * 8)]);
      }
    }
#pragma unroll
    for (int c = 0; c < 2; ++c)
#pragma unroll
      for (int m = 0; m < 4; ++m)
#pragma unroll
        for (int n = 0; n < 4; ++n)
          acc[m][n] = __builtin_amdgcn_mfma_f32_16x16x32_bf16(af[c][m], bfr[c][n], acc[m][n], 0, 0, 0);
    __builtin_amdgcn_s_barrier();
    __builtin_amdgcn_sched_barrier(0);
  }

  int rbase = bm * 128 + wr * 64;
  int cbase = bn * 128 + wc * 64;
#pragma unroll
  for (int m = 0; m < 4; ++m)
#pragma unroll
    for (int n = 0; n < 4; ++n) {
      int row0 = rbase + m * 16 + (lane >> 4) * 4;
      int col = cbase + n * 16 + (lane & 15);
#pragma unroll
      for (int reg = 0; reg < 4; ++reg)
        dst[(size_t)(row0 + reg) * 1024 + col] = acc[m][n][reg];
    }
}

// ---------------- sparse attention ----------------
// R12 structure + occupancy fix: K 2-deep (3 buffers) + V 1-deep (2 buffers)
// = 40KB LDS -> 4 blocks/CU (was 48KB -> 3). Issue order per iter:
// vmcnt(2) [drains K(t),V(t); keeps K(t+1)] -> barrier -> issue V(t+1), K(t+2).
// Prologue: K0, V0, K1 (oldest-first drain leaves K1 in flight at iter 0).
__global__ __launch_bounds__(256) void attn_kernel(const unsigned short* __restrict__ Qh,
                            const unsigned short* __restrict__ Kh,
                            const unsigned short* __restrict__ Vbt,
                            const int* __restrict__ bidx,
                            unsigned short* __restrict__ attn_out,
                            float* __restrict__ Opart,
                            float* __restrict__ lpart) {
  __shared__ __align__(16) unsigned short Ks[3][64 * 64];
  __shared__ __align__(16) unsigned short Vs[2][64 * 64];
  int flat = blockIdx.x + 71 * blockIdx.y;
  int nf = (flat & 7) * 284 + (flat >> 3);  // bijective chunked XCD swizzle
  int gx = nf % 71, bh = nf / 71;
  int h = bh & 15;
  int tid = threadIdx.x, lane = tid & 63, w = tid >> 6;
  int q = lane & 15, g = lane >> 4;
  float slope2 = exp2f(-0.5f * (float)(h + 1)) * 1.44269504f;  // slope * log2(e)

  int qb, nkb;
  int vlist;
  if (gx < 63) {
    qb = gx + 1;
    int v = -1;
    if (lane == 0) v = 0;
    else if (lane <= 12) v = bidx[qb * 12 + (lane - 1)];
    vlist = v;
    unsigned long long msk = __ballot(v >= 0);
    nkb = __builtin_popcountll(msk & 0x1FFFull);
  } else {
    qb = 0;
    nkb = 8;
    vlist = (gx - 63) * 8 + lane;  // lanes 0..7 hold the chunk's blocks
  }

  int qrow = qb * 64 + w * 16 + q;
  const unsigned short* qptr = Qh + ((size_t)bh * 4096 + qrow) * 64 + g * 8;
  short8 qf0 = *(const short8*)qptr;
  short8 qf1 = *(const short8*)(qptr + 32);

  float qposf = (float)qrow;
  float sq = slope2 * qposf;
  float er[4][4];
#pragma unroll
  for (int ct = 0; ct < 4; ++ct)
#pragma unroll
    for (int r = 0; r < 4; ++r) er[ct][r] = slope2 * (float)(ct * 16 + r);

  float psum = 0.f;
  f32x4 accO[4] = {};

  const unsigned short* Kbh = Kh + (size_t)bh * 4096 * 64;
  const unsigned short* Vbh = Vbt + (size_t)bh * 4096 * 64;

  int srr[2], so[2];
#pragma unroll
  for (int i = 0; i < 2; ++i) {
    int ci = w * 2 + i;
    int r = ci * 8 + (lane >> 3);
    srr[i] = r;
    so[i] = ((lane & 7) ^ (r & 7)) * 8;
  }
  auto STAGE_K = [&](int bi, int kb) {
    const unsigned short* kbase = Kbh + (size_t)kb * 4096;
#pragma unroll
    for (int i = 0; i < 2; ++i)
      gload16(kbase + srr[i] * 64 + so[i], &Ks[bi][(w * 2 + i) * 512]);
  };
  auto STAGE_V = [&](int bi, int kb) {
    const unsigned short* vbase = Vbh + (size_t)kb * 4096;
#pragma unroll
    for (int i = 0; i < 2; ++i)
      gload16(vbase + srr[i] * 64 + so[i], &Vs[bi][(w * 2 + i) * 512]);
  };

  // prologue: K0, V0, K1 (order matters for the oldest-first vmcnt drain)
  STAGE_K(0, __builtin_amdgcn_readlane(vlist, 0));
  STAGE_V(0, __builtin_amdgcn_readlane(vlist, 0));
  STAGE_K(1, __builtin_amdgcn_readlane(vlist, 1));

  for (int it = 0; it < nkb; ++it) {
    int curK = it % 3, curV = it & 1;
    int kb = __builtin_amdgcn_readlane(vlist, it);
    if (it + 1 < nkb) {
      asm volatile("s_waitcnt vmcnt(2)" ::: "memory");  // K(t),V(t) landed; K(t+1) in flight
    } else {
      asm volatile("s_waitcnt vmcnt(0)" ::: "memory");
    }
    __builtin_amdgcn_s_barrier();
    __builtin_amdgcn_sched_barrier(0);
    if (it + 1 < nkb) STAGE_V((it + 1) & 1, __builtin_amdgcn_readlane(vlist, it + 1));
    if (it + 2 < nkb) STAGE_K((it + 2) % 3, __builtin_amdgcn_readlane(vlist, it + 2));

    float kb4g = (float)(kb * 64 + 4 * g);
    float d_[4][4];
    if (kb != qb) {
      if (kb < qb) {
        float t = __builtin_fmaf(slope2, kb4g, -sq);
#pragma unroll
        for (int ct = 0; ct < 4; ++ct)
#pragma unroll
          for (int r = 0; r < 4; ++r) d_[ct][r] = t + er[ct][r];
      } else {
        float t = sq - slope2 * kb4g;
#pragma unroll
        for (int ct = 0; ct < 4; ++ct)
#pragma unroll
          for (int r = 0; r < 4; ++r) d_[ct][r] = t - er[ct][r];
      }
    } else {
      float db = qposf - kb4g;
#pragma unroll
      for (int ct = 0; ct < 4; ++ct)
#pragma unroll
        for (int r = 0; r < 4; ++r)
          d_[ct][r] = -slope2 * fabsf(db - (float)(ct * 16 + r));
    }

    float pv[4][4];
    __builtin_amdgcn_s_setprio(1);
#pragma unroll
    for (int ct = 0; ct < 4; ++ct) {
      int kr = ct * 16 + q;
      short8 kf0 = *(const short8*)(&Ks[curK][kr * 64 + ((g ^ (kr & 7)) * 8)]);
      short8 kf1 = *(const short8*)(&Ks[curK][kr * 64 + (((g + 4) ^ (kr & 7)) * 8)]);
      f32x4 cin = {d_[ct][0], d_[ct][1], d_[ct][2], d_[ct][3]};
      f32x4 s = __builtin_amdgcn_mfma_f32_16x16x32_bf16(kf0, qf0, cin, 0, 0, 0);
      s = __builtin_amdgcn_mfma_f32_16x16x32_bf16(kf1, qf1, s, 0, 0, 0);
#pragma unroll
      for (int r = 0; r < 4; ++r) {
        float p = exp2f(s[r]);
        pv[ct][r] = p;
        psum += p;
      }
    }
    __builtin_amdgcn_s_setprio(0);

    // in-register P^T -> PV A-fragment redistribution (T12)
    uint32_t pkw[4][2];
#pragma unroll
    for (int ct = 0; ct < 4; ++ct) {
      asm("v_cvt_pk_bf16_f32 %0, %1, %2" : "=v"(pkw[ct][0]) : "v"(pv[ct][0]), "v"(pv[ct][1]));
      asm("v_cvt_pk_bf16_f32 %0, %1, %2" : "=v"(pkw[ct][1]) : "v"(pv[ct][2]), "v"(pv[ct][3]));
    }
    bool odd = (tid & 16) != 0;
    short8 pa[2];
#pragma unroll
    for (int f = 0; f < 2; ++f) {
      uint32_t s0 = pkw[2 * f][0], s1 = pkw[2 * f][1];
      uint32_t t0 = pkw[2 * f + 1][0], t1 = pkw[2 * f + 1][1];
      asm("v_permlane32_swap_b32 %0, %1" : "+v"(s0), "+v"(t0));
      asm("v_permlane32_swap_b32 %0, %1" : "+v"(s1), "+v"(t1));
      uint32_t xs0 = (uint32_t)__shfl_xor((int)s0, 16, 64);
      uint32_t xs1 = (uint32_t)__shfl_xor((int)s1, 16, 64);
      uint32_t xt0 = (uint32_t)__shfl_xor((int)t0, 16, 64);
      uint32_t xt1 = (uint32_t)__shfl_xor((int)t1, 16, 64);
      union { uint32_t w[4]; short8 v; } u;
      u.w[0] = odd ? xt0 : s0;
      u.w[1] = odd ? xt1 : s1;
      u.w[2] = odd ? t0 : xs0;
      u.w[3] = odd ? t1 : xs1;
      pa[f] = u.v;
    }

    __builtin_amdgcn_s_setprio(1);
#pragma unroll
    for (int dt = 0; dt < 4; ++dt) {
      int dr = dt * 16 + q;
      short8 vf0 = *(const short8*)(&Vs[curV][dr * 64 + ((g ^ (dr & 7)) * 8)]);
      short8 vf1 = *(const short8*)(&Vs[curV][dr * 64 + (((g + 4) ^ (dr & 7)) * 8)]);
      accO[dt] = __builtin_amdgcn_mfma_f32_16x16x32_bf16(pa[0], vf0, accO[dt], 0, 0, 0);
      accO[dt] = __builtin_amdgcn_mfma_f32_16x16x32_bf16(pa[1], vf1, accO[dt], 0, 0, 0);
    }
    __builtin_amdgcn_s_setprio(0);
  }

  float lt = psum;
  lt += __shfl_xor(lt, 16, 64);
  lt += __shfl_xor(lt, 32, 64);

  int b = bh >> 4;
  if (gx < 63) {
#pragma unroll
    for (int reg = 0; reg < 4; ++reg) {
      float ls = __shfl(lt, 4 * g + reg, 64);
      float rl = 1.0f / ls;
      int row = qb * 64 + w * 16 + 4 * g + reg;
#pragma unroll
      for (int dt = 0; dt < 4; ++dt) {
        int col = h * 64 + dt * 16 + q;
        attn_out[((size_t)b * 4096 + row) * 1024 + col] = f2bf(accO[dt][reg] * rl);
      }
    }
  } else {
    int chunk = gx - 63;
    float* Op = Opart + (size_t)(bh * 8 + chunk) * 64 * 64;
    float* lp = lpart + (size_t)(bh * 8 + chunk) * 64;
#pragma unroll
    for (int reg = 0; reg < 4; ++reg) {
      int row = w * 16 + 4 * g + reg;
#pragma unroll
      for (int dt = 0; dt < 4; ++dt) {
        int col = dt * 16 + q;
        Op[row * 64 + col] = accO[dt][reg];
      }
    }
    if (g == 0) lp[w * 16 + q] = lt;
  }
}

// ---------------- merge the 8 qb=0 chunks ----------------
__global__ void merge_qb0(const float* __restrict__ Opart, const float* __restrict__ lpart,
                          unsigned short* __restrict__ attn_out) {
  int bh = blockIdx.x;
  int tid = threadIdx.x;
  int row = tid >> 2, cg = tid & 3;
  const float* lp = lpart + (size_t)bh * 8 * 64;
  float L = 0.f;
#pragma unroll
  for (int c = 0; c < 8; ++c) L += lp[c * 64 + row];
  float rL = 1.0f / L;
  int b = bh >> 4, h = bh & 15;
  f32x4 acc0 = {}, acc1 = {}, acc2 = {}, acc3 = {};
#pragma unroll
  for (int c = 0; c < 8; ++c) {
    const float* Op = Opart + ((size_t)(bh * 8 + c) * 64 + row) * 64 + cg * 16;
    acc0 += ((const f32x4*)Op)[0];
    acc1 += ((const f32x4*)Op)[1];
    acc2 += ((const f32x4*)Op)[2];
    acc3 += ((const f32x4*)Op)[3];
  }
  unsigned short* out = attn_out + ((size_t)b * 4096 + row) * 1024 + h * 64 + cg * 16;
#pragma unroll
  for (int j = 0; j < 4; ++j) {
    out[j] = f2bf(acc0[j] * rL);
    out[4 + j] = f2bf(acc1[j] * rL);
    out[8 + j] = f2bf(acc2[j] * rL);
    out[12 + j] = f2bf(acc3[j] * rL);
  }
}

extern "C" void kernel_launch(void* const* d_in, const int* in_sizes, int n_in,
                              void* d_out, int out_size, void* d_ws, size_t ws_size,
                              hipStream_t stream) {
  const float* x = (const float*)d_in[0];
  const float* Wq = (const float*)d_in[1];
  const float* Wk = (const float*)d_in[2];
  const float* Wv = (const float*)d_in[3];
  const float* Wo = (const float*)d_in[4];
  const int* bidx = (const int*)d_in[5];

  char* ws = (char*)d_ws;
  unsigned short* xb = (unsigned short*)(ws);
  unsigned short* wt = (unsigned short*)(ws + 16777216);
  unsigned short* Qb = (unsigned short*)(ws + 25165824);
  unsigned short* Kb = (unsigned short*)(ws + 41943040);
  unsigned short* Vtb = (unsigned short*)(ws + 58720256);
  unsigned short* attnb = (unsigned short*)(ws + 75497472);
  float* Opart = (float*)(ws);
  float* lpart = (float*)(ws + 4194304);

  cast_x_kernel<<<4096, 256, 0, stream>>>(x, xb);
  transpose_w_kernel<<<dim3(16, 16, 4), 256, 0, stream>>>(Wq, Wk, Wv, Wo, wt);
  gemm_qkv<<<dim3(24, 64), 256, 0, stream>>>(xb, wt, Qb, Kb, Vtb, 0.18033688f);
  attn_kernel<<<dim3(71, 32), 256, 0, stream>>>(Qb, Kb, Vtb, bidx, attnb, Opart, lpart);
  merge_qb0<<<32, 256, 0, stream>>>(Opart, lpart, attnb);
  gemm_out<<<dim3(8, 64), 256, 0, stream>>>(attnb, wt + 3145728, (float*)d_out);
}